// Round 6
// baseline (511.914 us; speedup 1.0000x reference)
//
#include <hip/hip_runtime.h>
#include <hip/hip_bf16.h>
#include <stdint.h>

#define E_EDGES 500000
#define NNODES  50000
#define DN 128
#define DE 64
#define DH 256
#define DO 64
#define BE 32            // edges per tile; 500000/32 = 15625 exact, no tail
#define NTILES (E_EDGES / BE)
#define GRID 2048        // persistent blocks; ~7.6 tiles each
#define TS 528           // h octet-tile stride: 32 edges * 16B + 16B pad

typedef __attribute__((ext_vector_type(8))) short short8;
typedef __attribute__((ext_vector_type(4))) short short4v;
typedef __attribute__((ext_vector_type(4))) float f32x4;

__device__ __forceinline__ short f2bf(float f) {
    union { __hip_bfloat16 h; short s; } u;
    u.h = __float2bfloat16(f);
    return u.s;
}

// WcatT[512][128]: c<256 -> W1[k][c] (W1a^T), c>=256 -> W1[128+k][c-256] (W1b^T)
// W1cT [256][64] : W1[256+k][c] ; W2T [64][256] : W2[k][n]
__global__ void convert_weights(const float* __restrict__ W1, const float* __restrict__ W2,
                                short* __restrict__ WcatT, short* __restrict__ W1cT,
                                short* __restrict__ W2T) {
    int idx = blockIdx.x * 256 + threadIdx.x;
    if (idx < 512 * 128) {
        int c = idx >> 7, k = idx & 127;
        WcatT[idx] = f2bf(W1[(c < 256 ? k : k + 128) * DH + (c & 255)]);
    } else if (idx < 512 * 128 + 256 * 64) {
        int i = idx - 512 * 128;
        int c = i >> 6, k = i & 63;
        W1cT[i] = f2bf(W1[(256 + k) * DH + c]);
    } else if (idx < 512 * 128 + 256 * 64 + 64 * 256) {
        int i = idx - 512 * 128 - 256 * 64;
        int n = i >> 8, k = i & 255;
        W2T[i] = f2bf(W2[k * DO + n]);
    }
}

// PQ[50000][512] bf16 = [ nf@W1a + b1 | nf@W1b ]
__global__ __launch_bounds__(256, 4) void node_gemm(
    const float* __restrict__ nf, const short* __restrict__ WcatT,
    const float* __restrict__ b1, short* __restrict__ PQ)
{
    __shared__ __align__(16) short xt[64 * 128];   // [64][128] bf16, XOR-swizzled, 16KB
    const int tid = threadIdx.x, lane = tid & 63, wv = tid >> 6;
    const int lr = lane & 15, lk = lane >> 4;
    const int r0 = blockIdx.x * 64;
    const int cb = blockIdx.y * 256;
    char* xb = (char*)xt;

    {   // stage nf tile (rows clamped; garbage rows never stored)
        int r = tid >> 2, q = tid & 3;
        int gr = r0 + r; if (gr > NNODES - 1) gr = NNODES - 1;
        const float4* src = (const float4*)(nf + (long)gr * DN) + q * 8;
        #pragma unroll
        for (int i = 0; i < 4; ++i) {
            float4 a = src[2 * i], b = src[2 * i + 1];
            short8 s = { f2bf(a.x), f2bf(a.y), f2bf(a.z), f2bf(a.w),
                         f2bf(b.x), f2bf(b.y), f2bf(b.z), f2bf(b.w) };
            *(short8*)(xb + ((r * 256 + q * 64 + i * 16) ^ ((r & 7) << 4))) = s;
        }
    }
    __syncthreads();

    f32x4 acc[4][4];
    #pragma unroll
    for (int m = 0; m < 4; ++m)
        #pragma unroll
        for (int n = 0; n < 4; ++n)
            acc[m][n] = (f32x4){0.f, 0.f, 0.f, 0.f};

    #pragma unroll
    for (int kt = 0; kt < 4; ++kt) {
        short8 a[4], w[4];
        #pragma unroll
        for (int m = 0; m < 4; ++m) {
            int row = 16 * m + lr;
            a[m] = *(const short8*)(xb + ((row * 256 + kt * 64 + lk * 16) ^ ((row & 7) << 4)));
        }
        #pragma unroll
        for (int n = 0; n < 4; ++n)
            w[n] = *(const short8*)(WcatT + (long)(cb + wv * 64 + n * 16 + lr) * 128 + kt * 32 + lk * 8);
        #pragma unroll
        for (int m = 0; m < 4; ++m)
            #pragma unroll
            for (int n = 0; n < 4; ++n)
                acc[m][n] = __builtin_amdgcn_mfma_f32_16x16x32_bf16(w[n], a[m], acc[m][n], 0, 0, 0);
    }

    #pragma unroll
    for (int m = 0; m < 4; ++m) {
        int row = r0 + 16 * m + lr;
        if (row < NNODES) {
            #pragma unroll
            for (int n = 0; n < 4; ++n) {
                float4 bv = make_float4(0.f, 0.f, 0.f, 0.f);
                if (cb == 0) bv = *(const float4*)(b1 + wv * 64 + n * 16 + lk * 4);
                short4v s = { f2bf(acc[m][n][0] + bv.x), f2bf(acc[m][n][1] + bv.y),
                              f2bf(acc[m][n][2] + bv.z), f2bf(acc[m][n][3] + bv.w) };
                *(short4v*)(PQ + (long)row * 512 + cb + wv * 64 + n * 16 + lk * 4) = s;
            }
        }
    }
}

// per-edge: h = relu(P[row] + Q[col] + ea@W1c); out = h@W2 + b2   (b1 folded into P)
// P+Q injected via identity-MFMA; persistent grid-stride blocks for full occupancy.
__global__ __launch_bounds__(256, 8) void edge_mlp(
    const int* __restrict__ eidx, const float* __restrict__ ea,
    const short* __restrict__ PQ, const short* __restrict__ W1cT,
    const short* __restrict__ W2T, const float* __restrict__ b2,
    float* __restrict__ out)
{
    __shared__ __align__(16) char hbuf[32 * TS];

    const int tid = threadIdx.x, lane = tid & 63, wv = tid >> 6;
    const int lr = lane & 15, lk = lane >> 4;

    // identity A-fragment [I16 | I16]: A[r][k] = ((k & 15) == r) ? 1 : 0
    short8 ifrag;
    #pragma unroll
    for (int i = 0; i < 8; ++i)
        ifrag[i] = (((8 * lk + i) & 15) == lr) ? (short)0x3F80 : (short)0;

    const float4 bb = *(const float4*)(b2 + wv * 16 + lk * 4);

    for (int t = blockIdx.x; t < NTILES; t += GRID) {
        const long e0 = (long)t * BE;

        // edge indices for my two edges (m=0,1); lane lr owns edge 16m+lr
        const int ri0 = eidx[e0 + lr],      ci0 = eidx[E_EDGES + e0 + lr];
        const int ri1 = eidx[e0 + 16 + lr], ci1 = eidx[E_EDGES + e0 + 16 + lr];

        // P+Q inject fragments: lk<2 reads P[row], lk>=2 reads Q[col]
        const short* pb0 = (lk < 2) ? (PQ + (long)ri0 * 512 + wv * 64)
                                    : (PQ + (long)ci0 * 512 + 256 + wv * 64);
        const short* pb1 = (lk < 2) ? (PQ + (long)ri1 * 512 + wv * 64)
                                    : (PQ + (long)ci1 * 512 + 256 + wv * 64);
        short8 pq0[4], pq1[4];
        #pragma unroll
        for (int n = 0; n < 4; ++n) {
            pq0[n] = *(const short8*)(pb0 + n * 16 + (lk & 1) * 8);
            pq1[n] = *(const short8*)(pb1 + n * 16 + (lk & 1) * 8);
        }

        // ---- acc = ea @ W1c (swapped mfma: D col = edge, D row = hcol) ----
        f32x4 acc[2][4];
        #pragma unroll
        for (int m = 0; m < 2; ++m)
            #pragma unroll
            for (int n = 0; n < 4; ++n)
                acc[m][n] = (f32x4){0.f, 0.f, 0.f, 0.f};

        #pragma unroll
        for (int kt = 0; kt < 2; ++kt) {
            short8 w[4], eb[2];
            #pragma unroll
            for (int n = 0; n < 4; ++n)
                w[n] = *(const short8*)(W1cT + (wv * 64 + n * 16 + lr) * 64 + kt * 32 + lk * 8);
            #pragma unroll
            for (int m = 0; m < 2; ++m) {
                const float4* s = (const float4*)(ea + (e0 + 16 * m + lr) * DE + kt * 32 + lk * 8);
                float4 x = s[0], y = s[1];
                eb[m] = (short8){ f2bf(x.x), f2bf(x.y), f2bf(x.z), f2bf(x.w),
                                  f2bf(y.x), f2bf(y.y), f2bf(y.z), f2bf(y.w) };
            }
            #pragma unroll
            for (int m = 0; m < 2; ++m)
                #pragma unroll
                for (int n = 0; n < 4; ++n)
                    acc[m][n] = __builtin_amdgcn_mfma_f32_16x16x32_bf16(w[n], eb[m], acc[m][n], 0, 0, 0);
        }

        // ---- acc += P + Q via identity-MFMA ----
        #pragma unroll
        for (int n = 0; n < 4; ++n) {
            acc[0][n] = __builtin_amdgcn_mfma_f32_16x16x32_bf16(ifrag, pq0[n], acc[0][n], 0, 0, 0);
            acc[1][n] = __builtin_amdgcn_mfma_f32_16x16x32_bf16(ifrag, pq1[n], acc[1][n], 0, 0, 0);
        }

        __syncthreads();   // previous tile's GEMM2 LDS reads complete before overwrite

        // ---- h = relu(acc) -> bf16 -> octet-tile LDS ----
        #pragma unroll
        for (int m = 0; m < 2; ++m) {
            const int e = 16 * m + lr;
            #pragma unroll
            for (int n = 0; n < 4; ++n) {
                const int o = 8 * wv + 2 * n + (lk >> 1);       // hcol>>3
                short4v hs = { f2bf(fmaxf(acc[m][n][0], 0.f)),
                               f2bf(fmaxf(acc[m][n][1], 0.f)),
                               f2bf(fmaxf(acc[m][n][2], 0.f)),
                               f2bf(fmaxf(acc[m][n][3], 0.f)) };
                *(short4v*)(hbuf + o * TS + e * 16 + (lk & 1) * 8) = hs;
            }
        }
        __syncthreads();

        // ---- out = h @ W2 + b2 (swapped: D col = edge, D row = out-col) ----
        f32x4 acc2[2];
        acc2[0] = (f32x4){0.f, 0.f, 0.f, 0.f};
        acc2[1] = (f32x4){0.f, 0.f, 0.f, 0.f};

        #pragma unroll
        for (int kt = 0; kt < 8; ++kt) {
            short8 w2 = *(const short8*)(W2T + (wv * 16 + lr) * 256 + kt * 32 + lk * 8);
            #pragma unroll
            for (int m = 0; m < 2; ++m) {
                short8 hb = *(const short8*)(hbuf + (4 * kt + lk) * TS + (16 * m + lr) * 16);
                acc2[m] = __builtin_amdgcn_mfma_f32_16x16x32_bf16(w2, hb, acc2[m], 0, 0, 0);
            }
        }

        #pragma unroll
        for (int m = 0; m < 2; ++m) {
            long ge = e0 + 16 * m + lr;
            float4 o;
            o.x = acc2[m][0] + bb.x;
            o.y = acc2[m][1] + bb.y;
            o.z = acc2[m][2] + bb.z;
            o.w = acc2[m][3] + bb.w;
            *(float4*)(out + ge * DO + wv * 16 + lk * 4) = o;
        }
    }
}

extern "C" void kernel_launch(void* const* d_in, const int* in_sizes, int n_in,
                              void* d_out, int out_size, void* d_ws, size_t ws_size,
                              hipStream_t stream) {
    const float* node_feats = (const float*)d_in[0];
    const int*   eidx       = (const int*)d_in[1];
    const float* edge_attr  = (const float*)d_in[2];
    const float* W1         = (const float*)d_in[3];
    const float* b1         = (const float*)d_in[4];
    const float* W2         = (const float*)d_in[5];
    const float* b2         = (const float*)d_in[6];
    float* out = (float*)d_out;

    short* WcatT = (short*)d_ws;            // 512*128
    short* W1cT  = WcatT + 512 * 128;       // 256*64
    short* W2T   = W1cT + 256 * 64;         // 64*256
    short* PQ    = W2T + 64 * 256;          // 50000*512 bf16 (~51.2MB)

    convert_weights<<<384, 256, 0, stream>>>(W1, W2, WcatT, W1cT, W2T);
    node_gemm<<<dim3(782, 2), 256, 0, stream>>>(node_feats, WcatT, b1, PQ);
    edge_mlp<<<GRID, 256, 0, stream>>>(eidx, edge_attr, PQ, W1cT, W2T, b2, out);
}

// Round 7
// 272.083 us; speedup vs baseline: 1.8815x; 1.8815x over previous
//
#include <hip/hip_runtime.h>
#include <hip/hip_bf16.h>
#include <stdint.h>

#define E_EDGES 500000
#define NNODES  50000
#define DN 128
#define DE 64
#define DH 256
#define DO 64
#define BE 32            // edges per tile; 500000/32 = 15625 tiles
#define NTILES (E_EDGES / BE)
#define NBLK ((NTILES + 1) / 2)   // 2 tiles per block
#define TS 528           // h octet-tile stride: 32 edges * 16B + 16B pad

typedef __attribute__((ext_vector_type(8))) short short8;
typedef __attribute__((ext_vector_type(4))) short short4v;
typedef __attribute__((ext_vector_type(4))) float f32x4;

__device__ __forceinline__ short f2bf(float f) {
    union { __hip_bfloat16 h; short s; } u;
    u.h = __float2bfloat16(f);
    return u.s;
}

// WcatT[512][128]: c<256 -> W1[k][c] (W1a^T), c>=256 -> W1[128+k][c-256] (W1b^T)
// W1cT [256][64] : W1[256+k][c] ; W2T [64][256] : W2[k][n]
__global__ void convert_weights(const float* __restrict__ W1, const float* __restrict__ W2,
                                short* __restrict__ WcatT, short* __restrict__ W1cT,
                                short* __restrict__ W2T) {
    int idx = blockIdx.x * 256 + threadIdx.x;
    if (idx < 512 * 128) {
        int c = idx >> 7, k = idx & 127;
        WcatT[idx] = f2bf(W1[(c < 256 ? k : k + 128) * DH + (c & 255)]);
    } else if (idx < 512 * 128 + 256 * 64) {
        int i = idx - 512 * 128;
        int c = i >> 6, k = i & 63;
        W1cT[i] = f2bf(W1[(256 + k) * DH + c]);
    } else if (idx < 512 * 128 + 256 * 64 + 64 * 256) {
        int i = idx - 512 * 128 - 256 * 64;
        int n = i >> 8, k = i & 255;
        W2T[i] = f2bf(W2[k * DO + n]);
    }
}

// PQ[50000][512] bf16 = [ nf@W1a + b1 | nf@W1b ]
__global__ __launch_bounds__(256, 4) void node_gemm(
    const float* __restrict__ nf, const short* __restrict__ WcatT,
    const float* __restrict__ b1, short* __restrict__ PQ)
{
    __shared__ __align__(16) short xt[64 * 128];   // [64][128] bf16, XOR-swizzled, 16KB
    const int tid = threadIdx.x, lane = tid & 63, wv = tid >> 6;
    const int lr = lane & 15, lk = lane >> 4;
    const int r0 = blockIdx.x * 64;
    const int cb = blockIdx.y * 256;
    char* xb = (char*)xt;

    {   // stage nf tile (rows clamped; garbage rows never stored)
        int r = tid >> 2, q = tid & 3;
        int gr = r0 + r; if (gr > NNODES - 1) gr = NNODES - 1;
        const float4* src = (const float4*)(nf + (long)gr * DN) + q * 8;
        #pragma unroll
        for (int i = 0; i < 4; ++i) {
            float4 a = src[2 * i], b = src[2 * i + 1];
            short8 s = { f2bf(a.x), f2bf(a.y), f2bf(a.z), f2bf(a.w),
                         f2bf(b.x), f2bf(b.y), f2bf(b.z), f2bf(b.w) };
            *(short8*)(xb + ((r * 256 + q * 64 + i * 16) ^ ((r & 7) << 4))) = s;
        }
    }
    __syncthreads();

    f32x4 acc[4][4];
    #pragma unroll
    for (int m = 0; m < 4; ++m)
        #pragma unroll
        for (int n = 0; n < 4; ++n)
            acc[m][n] = (f32x4){0.f, 0.f, 0.f, 0.f};

    #pragma unroll
    for (int kt = 0; kt < 4; ++kt) {
        short8 a[4], w[4];
        #pragma unroll
        for (int m = 0; m < 4; ++m) {
            int row = 16 * m + lr;
            a[m] = *(const short8*)(xb + ((row * 256 + kt * 64 + lk * 16) ^ ((row & 7) << 4)));
        }
        #pragma unroll
        for (int n = 0; n < 4; ++n)
            w[n] = *(const short8*)(WcatT + (long)(cb + wv * 64 + n * 16 + lr) * 128 + kt * 32 + lk * 8);
        #pragma unroll
        for (int m = 0; m < 4; ++m)
            #pragma unroll
            for (int n = 0; n < 4; ++n)
                acc[m][n] = __builtin_amdgcn_mfma_f32_16x16x32_bf16(w[n], a[m], acc[m][n], 0, 0, 0);
    }

    #pragma unroll
    for (int m = 0; m < 4; ++m) {
        int row = r0 + 16 * m + lr;
        if (row < NNODES) {
            #pragma unroll
            for (int n = 0; n < 4; ++n) {
                float4 bv = make_float4(0.f, 0.f, 0.f, 0.f);
                if (cb == 0) bv = *(const float4*)(b1 + wv * 64 + n * 16 + lk * 4);
                short4v s = { f2bf(acc[m][n][0] + bv.x), f2bf(acc[m][n][1] + bv.y),
                              f2bf(acc[m][n][2] + bv.z), f2bf(acc[m][n][3] + bv.w) };
                *(short4v*)(PQ + (long)row * 512 + cb + wv * 64 + n * 16 + lk * 4) = s;
            }
        }
    }
}

// per-edge: h = relu(P[row]+Q[col]+ea@W1c); out = h@W2+b2  (b1 folded into P)
// 2 tiles per block, software-pipelined, ONE barrier per block.
__global__ __launch_bounds__(256, 4) void edge_mlp(
    const int* __restrict__ eidx, const float* __restrict__ ea,
    const short* __restrict__ PQ, const short* __restrict__ W1cT,
    const short* __restrict__ W2T, const float* __restrict__ b2,
    float* __restrict__ out)
{
    __shared__ __align__(16) char hbuf[2][32 * TS];

    const int tid = threadIdx.x, lane = tid & 63, wv = tid >> 6;
    const int lr = lane & 15, lk = lane >> 4;

    // identity A-fragment [I16 | I16]: A[r][k] = ((k & 15) == r) ? 1 : 0
    short8 ifrag;
    #pragma unroll
    for (int i = 0; i < 8; ++i)
        ifrag[i] = (((8 * lk + i) & 15) == lr) ? (short)0x3F80 : (short)0;

    const float4 bb = *(const float4*)(b2 + wv * 16 + lk * 4);

    const long t0 = 2L * blockIdx.x;
    const bool has1 = (t0 + 1 < NTILES);
    const long e0 = t0 * BE;
    const long e1 = e0 + (has1 ? BE : 0);   // clamp: last odd tile recomputed, store guarded

#define LOAD_TILE(E, PQF, EBF)                                                    \
    {                                                                             \
        const int ri0 = eidx[(E) + lr],      ci0 = eidx[E_EDGES + (E) + lr];      \
        const int ri1 = eidx[(E) + 16 + lr], ci1 = eidx[E_EDGES + (E) + 16 + lr]; \
        const short* pb0 = (lk < 2) ? (PQ + (long)ri0 * 512 + wv * 64)            \
                                    : (PQ + (long)ci0 * 512 + 256 + wv * 64);     \
        const short* pb1 = (lk < 2) ? (PQ + (long)ri1 * 512 + wv * 64)            \
                                    : (PQ + (long)ci1 * 512 + 256 + wv * 64);     \
        _Pragma("unroll")                                                         \
        for (int n = 0; n < 4; ++n) {                                             \
            PQF[0][n] = *(const short8*)(pb0 + n * 16 + (lk & 1) * 8);            \
            PQF[1][n] = *(const short8*)(pb1 + n * 16 + (lk & 1) * 8);            \
        }                                                                         \
        _Pragma("unroll")                                                         \
        for (int m = 0; m < 2; ++m)                                               \
            _Pragma("unroll")                                                     \
            for (int kt = 0; kt < 2; ++kt) {                                      \
                const float4* s = (const float4*)(ea + ((E) + 16 * m + lr) * DE + kt * 32 + lk * 8); \
                float4 x = s[0], y = s[1];                                        \
                EBF[m][kt] = (short8){ f2bf(x.x), f2bf(x.y), f2bf(x.z), f2bf(x.w),\
                                       f2bf(y.x), f2bf(y.y), f2bf(y.z), f2bf(y.w) }; \
            }                                                                     \
    }

#define COMP_TILE(PQF, EBF, ACC)                                                  \
    {                                                                             \
        const f32x4 zz = (f32x4){0.f, 0.f, 0.f, 0.f};                             \
        _Pragma("unroll")                                                         \
        for (int n = 0; n < 4; ++n) {                                             \
            ACC[0][n] = __builtin_amdgcn_mfma_f32_16x16x32_bf16(ifrag, PQF[0][n], zz, 0, 0, 0); \
            ACC[1][n] = __builtin_amdgcn_mfma_f32_16x16x32_bf16(ifrag, PQF[1][n], zz, 0, 0, 0); \
        }                                                                         \
        _Pragma("unroll")                                                         \
        for (int kt = 0; kt < 2; ++kt) {                                          \
            short8 w[4];                                                          \
            _Pragma("unroll")                                                     \
            for (int n = 0; n < 4; ++n)                                           \
                w[n] = *(const short8*)(W1cT + (wv * 64 + n * 16 + lr) * 64 + kt * 32 + lk * 8); \
            _Pragma("unroll")                                                     \
            for (int m = 0; m < 2; ++m)                                           \
                _Pragma("unroll")                                                 \
                for (int n = 0; n < 4; ++n)                                       \
                    ACC[m][n] = __builtin_amdgcn_mfma_f32_16x16x32_bf16(w[n], EBF[m][kt], ACC[m][n], 0, 0, 0); \
        }                                                                         \
    }

#define HWRITE(ACC, BUF)                                                          \
    _Pragma("unroll")                                                             \
    for (int m = 0; m < 2; ++m) {                                                 \
        const int e = 16 * m + lr;                                                \
        _Pragma("unroll")                                                         \
        for (int n = 0; n < 4; ++n) {                                             \
            const int o = 8 * wv + 2 * n + (lk >> 1);                             \
            short4v hs = { f2bf(fmaxf(ACC[m][n][0], 0.f)),                        \
                           f2bf(fmaxf(ACC[m][n][1], 0.f)),                        \
                           f2bf(fmaxf(ACC[m][n][2], 0.f)),                        \
                           f2bf(fmaxf(ACC[m][n][3], 0.f)) };                      \
            *(short4v*)((BUF) + o * TS + e * 16 + (lk & 1) * 8) = hs;             \
        }                                                                         \
    }

    f32x4 acc[2][4];
    {
        short8 pqf[2][4], ebf[2][2];
        LOAD_TILE(e0, pqf, ebf)
        COMP_TILE(pqf, ebf, acc)
    }
    {
        short8 pqg[2][4], ebg[2][2];
        LOAD_TILE(e1, pqg, ebg)          // issued under tile0's epilogue
        HWRITE(acc, hbuf[0])
        COMP_TILE(pqg, ebg, acc)         // reuse acc registers
        HWRITE(acc, hbuf[1])
    }

    __syncthreads();

    // fused GEMM2 for both tiles: W2 fragments loaded once
    f32x4 acc2[2][2];
    #pragma unroll
    for (int t = 0; t < 2; ++t)
        #pragma unroll
        for (int m = 0; m < 2; ++m)
            acc2[t][m] = (f32x4){0.f, 0.f, 0.f, 0.f};

    #pragma unroll
    for (int kt = 0; kt < 8; ++kt) {
        short8 w2 = *(const short8*)(W2T + (wv * 16 + lr) * 256 + kt * 32 + lk * 8);
        #pragma unroll
        for (int m = 0; m < 2; ++m) {
            short8 h0 = *(const short8*)(hbuf[0] + (4 * kt + lk) * TS + (16 * m + lr) * 16);
            acc2[0][m] = __builtin_amdgcn_mfma_f32_16x16x32_bf16(w2, h0, acc2[0][m], 0, 0, 0);
            short8 h1 = *(const short8*)(hbuf[1] + (4 * kt + lk) * TS + (16 * m + lr) * 16);
            acc2[1][m] = __builtin_amdgcn_mfma_f32_16x16x32_bf16(w2, h1, acc2[1][m], 0, 0, 0);
        }
    }

    #pragma unroll
    for (int m = 0; m < 2; ++m) {
        long ge = e0 + 16 * m + lr;
        float4 o;
        o.x = acc2[0][m][0] + bb.x;
        o.y = acc2[0][m][1] + bb.y;
        o.z = acc2[0][m][2] + bb.z;
        o.w = acc2[0][m][3] + bb.w;
        *(float4*)(out + ge * DO + wv * 16 + lk * 4) = o;
    }
    if (has1) {
        #pragma unroll
        for (int m = 0; m < 2; ++m) {
            long ge = e1 + 16 * m + lr;
            float4 o;
            o.x = acc2[1][m][0] + bb.x;
            o.y = acc2[1][m][1] + bb.y;
            o.z = acc2[1][m][2] + bb.z;
            o.w = acc2[1][m][3] + bb.w;
            *(float4*)(out + ge * DO + wv * 16 + lk * 4) = o;
        }
    }
#undef LOAD_TILE
#undef COMP_TILE
#undef HWRITE
}

extern "C" void kernel_launch(void* const* d_in, const int* in_sizes, int n_in,
                              void* d_out, int out_size, void* d_ws, size_t ws_size,
                              hipStream_t stream) {
    const float* node_feats = (const float*)d_in[0];
    const int*   eidx       = (const int*)d_in[1];
    const float* edge_attr  = (const float*)d_in[2];
    const float* W1         = (const float*)d_in[3];
    const float* b1         = (const float*)d_in[4];
    const float* W2         = (const float*)d_in[5];
    const float* b2         = (const float*)d_in[6];
    float* out = (float*)d_out;

    short* WcatT = (short*)d_ws;            // 512*128
    short* W1cT  = WcatT + 512 * 128;       // 256*64
    short* W2T   = W1cT + 256 * 64;         // 64*256
    short* PQ    = W2T + 64 * 256;          // 50000*512 bf16 (~51.2MB)

    convert_weights<<<384, 256, 0, stream>>>(W1, W2, WcatT, W1cT, W2T);
    node_gemm<<<dim3(782, 2), 256, 0, stream>>>(node_feats, WcatT, b1, PQ);
    edge_mlp<<<NBLK, 256, 0, stream>>>(eidx, edge_attr, PQ, W1cT, W2T, b2, out);
}